// Round 1
// baseline (1357.283 us; speedup 1.0000x reference)
//
#include <hip/hip_runtime.h>

typedef unsigned int u32;
typedef unsigned short u16;
typedef short s16x8 __attribute__((ext_vector_type(8)));
typedef float f32x4 __attribute__((ext_vector_type(4)));

// ---------- helpers ----------
__device__ __forceinline__ u16 f2bf(float f) {
  u32 u = __float_as_uint(f);
  u32 r = (u + 0x7fffu + ((u >> 16) & 1u)) >> 16;  // RNE
  return (u16)r;
}

// ---------- fp32 -> bf16 convert (vectorized) ----------
__global__ __launch_bounds__(256) void cvt_bf16_kernel(const float* __restrict__ src,
                                                       u16* __restrict__ dst, int n4) {
  int i = blockIdx.x * 256 + threadIdx.x;
  if (i >= n4) return;
  float4 v = reinterpret_cast<const float4*>(src)[i];
  u32 lo = (u32)f2bf(v.x) | ((u32)f2bf(v.y) << 16);
  u32 hi = (u32)f2bf(v.z) | ((u32)f2bf(v.w) << 16);
  reinterpret_cast<uint2*>(dst)[i] = make_uint2(lo, hi);
}

// ---------- build x = [emb[tok] ; thought] as bf16, rows m = s*16+b, K=1024 ----------
__global__ __launch_bounds__(128) void build_x_kernel(const int* __restrict__ tseq,
                                                      const float* __restrict__ emb,
                                                      const float* __restrict__ thought,
                                                      u16* __restrict__ x) {
  int m = blockIdx.x;  // 0..1023, m = s*16 + b
  int s = m >> 4, b = m & 15;
  int tid = threadIdx.x;  // 128
  int k = tid * 8;
  const float* src;
  if (k < 512) src = emb + (size_t)tseq[b * 64 + s] * 512 + k;
  else         src = thought + b * 512 + (k - 512);
  float4 v0 = reinterpret_cast<const float4*>(src)[0];
  float4 v1 = reinterpret_cast<const float4*>(src)[1];
  uint4 o;
  o.x = (u32)f2bf(v0.x) | ((u32)f2bf(v0.y) << 16);
  o.y = (u32)f2bf(v0.z) | ((u32)f2bf(v0.w) << 16);
  o.z = (u32)f2bf(v1.x) | ((u32)f2bf(v1.y) << 16);
  o.w = (u32)f2bf(v1.z) | ((u32)f2bf(v1.w) << 16);
  *reinterpret_cast<uint4*>(x + (size_t)m * 1024 + k) = o;
}

// ---------- bf16 MFMA GEMM: C[M,N] = A[M,K] * B[N,K]^T + bias, optional LSE partials ----------
// 128x128 tile, 256 threads (4 waves, 2x2), KT=32, LDS rows padded to 40 (bank-safe).
template <bool LSE>
__global__ __launch_bounds__(256) void gemm_bt_kernel(const u16* __restrict__ A,
                                                      const u16* __restrict__ Bm,
                                                      const float* __restrict__ bias,
                                                      float* __restrict__ C,
                                                      int M_, int N_, int K_,
                                                      float* __restrict__ partials, int nnb) {
  __shared__ u16 sA[128 * 40];
  __shared__ u16 sB[128 * 40];
  __shared__ float pm[2][128];
  __shared__ float ps[2][128];
  int nb = blockIdx.x, mb = blockIdx.y;
  int m0 = mb * 128, n0 = nb * 128;
  int tid = threadIdx.x;
  int wave = tid >> 6, lane = tid & 63;
  int wm = wave >> 1, wn = wave & 1;
  int l16 = lane & 15, quad = lane >> 4;
  int srow = tid >> 1, shalf = tid & 1;
  const u16* gA = A + (size_t)(m0 + srow) * K_ + shalf * 16;
  const u16* gB = Bm + (size_t)(n0 + srow) * K_ + shalf * 16;
  u16* lA = &sA[srow * 40 + shalf * 16];
  u16* lB = &sB[srow * 40 + shalf * 16];
  f32x4 acc[4][4];
  for (int i = 0; i < 4; ++i)
    for (int j = 0; j < 4; ++j) acc[i][j] = (f32x4){0.f, 0.f, 0.f, 0.f};

  for (int k0 = 0; k0 < K_; k0 += 32) {
    uint4 a0 = *reinterpret_cast<const uint4*>(gA + k0);
    uint4 a1 = *reinterpret_cast<const uint4*>(gA + k0 + 8);
    uint4 b0 = *reinterpret_cast<const uint4*>(gB + k0);
    uint4 b1 = *reinterpret_cast<const uint4*>(gB + k0 + 8);
    __syncthreads();
    *reinterpret_cast<uint4*>(lA) = a0;
    *reinterpret_cast<uint4*>(lA + 8) = a1;
    *reinterpret_cast<uint4*>(lB) = b0;
    *reinterpret_cast<uint4*>(lB + 8) = b1;
    __syncthreads();
    s16x8 af[4], bfr[4];
    for (int mt = 0; mt < 4; ++mt)
      af[mt] = *reinterpret_cast<const s16x8*>(&sA[(wm * 64 + mt * 16 + l16) * 40 + quad * 8]);
    for (int nt = 0; nt < 4; ++nt)
      bfr[nt] = *reinterpret_cast<const s16x8*>(&sB[(wn * 64 + nt * 16 + l16) * 40 + quad * 8]);
    for (int mt = 0; mt < 4; ++mt)
      for (int nt = 0; nt < 4; ++nt)
        acc[mt][nt] = __builtin_amdgcn_mfma_f32_16x16x32_bf16(af[mt], bfr[nt], acc[mt][nt], 0, 0, 0);
  }

  int rbase = wm * 64 + quad * 4;
  int cbase = n0 + wn * 64 + l16;
  for (int nt = 0; nt < 4; ++nt) {
    float bv = bias[cbase + nt * 16];
    for (int mt = 0; mt < 4; ++mt)
      for (int r = 0; r < 4; ++r) acc[mt][nt][r] += bv;
  }
  for (int mt = 0; mt < 4; ++mt)
    for (int r = 0; r < 4; ++r) {
      int row = m0 + rbase + mt * 16 + r;
      for (int nt = 0; nt < 4; ++nt)
        C[(size_t)row * N_ + cbase + nt * 16] = acc[mt][nt][r];
    }
  if (LSE) {
    for (int mt = 0; mt < 4; ++mt)
      for (int r = 0; r < 4; ++r) {
        float mx = acc[mt][0][r];
        for (int nt = 1; nt < 4; ++nt) mx = fmaxf(mx, acc[mt][nt][r]);
        for (int d = 1; d < 16; d <<= 1) mx = fmaxf(mx, __shfl_xor(mx, d));
        float sm = 0.f;
        for (int nt = 0; nt < 4; ++nt) sm += __expf(acc[mt][nt][r] - mx);
        for (int d = 1; d < 16; d <<= 1) sm += __shfl_xor(sm, d);
        if (l16 == 0) {
          int rr = wm * 64 + mt * 16 + quad * 4 + r;
          pm[wn][rr] = mx;
          ps[wn][rr] = sm;
        }
      }
    __syncthreads();
    if (tid < 128) {
      float m1 = pm[0][tid], m2 = pm[1][tid];
      float s1 = ps[0][tid], s2 = ps[1][tid];
      float Mx = fmaxf(m1, m2);
      float Sx = s1 * __expf(m1 - Mx) + s2 * __expf(m2 - Mx);
      float* p = partials + ((size_t)(m0 + tid) * nnb + nb) * 2;
      p[0] = Mx;
      p[1] = Sx;
    }
  }
}

// ---------- GRU recurrence ----------
// 512 WGs = 16 batches x 32 row-slices; each WG holds 48 rows of W_hh (bf16) in LDS.
// Per step: dot(48x512) -> gates for 16 hidden elems -> publish via agent-scope flags.
// LDS ~52KB -> 3 WG/CU capacity (768 slots >= 512 WGs): all resident, no deadlock.
__global__ __launch_bounds__(128) void gru_kernel(const float* __restrict__ gi,
                                                  const float* __restrict__ W_hh,
                                                  const float* __restrict__ b_hh,
                                                  const float* __restrict__ hidden,
                                                  float* __restrict__ hbuf,  // [2][16][512]
                                                  int* __restrict__ flags,   // [16][32]
                                                  u16* __restrict__ ys,      // [1024][512], m=b*64+t
                                                  float* __restrict__ hlast) {
  __shared__ u16 sW[48 * 520];   // padded stride 520 (bank-safe)
  __shared__ float h_s[576];     // padded: idx(j) = j + 4*(j>>5)
  __shared__ float gh_s[48];
  int wg = blockIdx.x;
  int b = wg >> 5, g = wg & 31;
  int tid = threadIdx.x;  // 128
  // load W slice: local row lr -> global row (lr>>4)*512 + g*16 + (lr&15)
  for (int lr = 0; lr < 48; ++lr) {
    int grow = (lr >> 4) * 512 + g * 16 + (lr & 15);
    const float* srcw = W_hh + (size_t)grow * 512;
    int k = tid * 4;
    float4 v = *reinterpret_cast<const float4*>(srcw + k);
    u16* dw = &sW[lr * 520 + k];
    dw[0] = f2bf(v.x); dw[1] = f2bf(v.y); dw[2] = f2bf(v.z); dw[3] = f2bf(v.w);
  }
  __syncthreads();
  int grp = tid >> 4, l16 = tid & 15;
  for (int t = 0; t < 64; ++t) {
    int par = t & 1;
    if (t > 0) {
      if (tid < 32) {
        int* fp = flags + b * 32 + tid;
        while (__hip_atomic_load(fp, __ATOMIC_ACQUIRE, __HIP_MEMORY_SCOPE_AGENT) < t)
          __builtin_amdgcn_s_sleep(2);
      }
      __syncthreads();
      float* hp = hbuf + (size_t)(par ^ 1) * 8192 + b * 512;
      for (int j = tid; j < 512; j += 128)
        h_s[j + ((j >> 5) << 2)] =
            __hip_atomic_load(hp + j, __ATOMIC_RELAXED, __HIP_MEMORY_SCOPE_AGENT);
    } else {
      const float* hp = hidden + b * 512;
      for (int j = tid; j < 512; j += 128) h_s[j + ((j >> 5) << 2)] = hp[j];
    }
    __syncthreads();
    // preload this lane's 32 h values (cols l16*32..+32)
    float hreg[32];
    int hb2 = l16 * 36;
    for (int c4 = 0; c4 < 4; ++c4) {
      float4 x0 = *reinterpret_cast<const float4*>(&h_s[hb2 + c4 * 8]);
      float4 x1 = *reinterpret_cast<const float4*>(&h_s[hb2 + c4 * 8 + 4]);
      hreg[c4 * 8 + 0] = x0.x; hreg[c4 * 8 + 1] = x0.y;
      hreg[c4 * 8 + 2] = x0.z; hreg[c4 * 8 + 3] = x0.w;
      hreg[c4 * 8 + 4] = x1.x; hreg[c4 * 8 + 5] = x1.y;
      hreg[c4 * 8 + 6] = x1.z; hreg[c4 * 8 + 7] = x1.w;
    }
    for (int p = 0; p < 6; ++p) {
      int lr = p * 8 + grp;
      const u16* wr = &sW[lr * 520 + l16 * 32];
      float acc = 0.f;
      for (int c4 = 0; c4 < 4; ++c4) {
        uint4 wv = *reinterpret_cast<const uint4*>(wr + c4 * 8);
        const float* hh = &hreg[c4 * 8];
        acc += __uint_as_float(wv.x << 16) * hh[0] + __uint_as_float(wv.x & 0xffff0000u) * hh[1];
        acc += __uint_as_float(wv.y << 16) * hh[2] + __uint_as_float(wv.y & 0xffff0000u) * hh[3];
        acc += __uint_as_float(wv.z << 16) * hh[4] + __uint_as_float(wv.z & 0xffff0000u) * hh[5];
        acc += __uint_as_float(wv.w << 16) * hh[6] + __uint_as_float(wv.w & 0xffff0000u) * hh[7];
      }
      acc += __shfl_xor(acc, 1);
      acc += __shfl_xor(acc, 2);
      acc += __shfl_xor(acc, 4);
      acc += __shfl_xor(acc, 8);
      if (l16 == 0) gh_s[lr] = acc;
    }
    __syncthreads();
    if (tid < 16) {
      int j = g * 16 + tid;
      size_t gib = ((size_t)t * 16 + b) * 1536;
      float ghr = gh_s[tid] + b_hh[j];
      float ghz = gh_s[16 + tid] + b_hh[512 + j];
      float ghn = gh_s[32 + tid] + b_hh[1024 + j];
      float r = 1.f / (1.f + __expf(-(gi[gib + j] + ghr)));
      float z = 1.f / (1.f + __expf(-(gi[gib + 512 + j] + ghz)));
      float n = tanhf(gi[gib + 1024 + j] + r * ghn);
      float hprev = h_s[j + ((j >> 5) << 2)];
      float hv = (1.f - z) * n + z * hprev;
      __hip_atomic_store(hbuf + (size_t)par * 8192 + b * 512 + j, hv,
                         __ATOMIC_RELAXED, __HIP_MEMORY_SCOPE_AGENT);
      ys[((size_t)b * 64 + t) * 512 + j] = f2bf(hv);
      if (t == 63) hlast[b * 512 + j] = hv;
    }
    __syncthreads();
    if (tid == 0)
      __hip_atomic_store(flags + b * 32 + g, t + 1, __ATOMIC_RELEASE, __HIP_MEMORY_SCOPE_AGENT);
  }
}

// ---------- combine per-row LSE partials ----------
__global__ __launch_bounds__(64) void lse_combine_kernel(const float* __restrict__ partials,
                                                         float* __restrict__ lse, int nnb) {
  int row = blockIdx.x;
  int lane = threadIdx.x;
  float M = -INFINITY, S = 0.f;
  for (int i = lane; i < nnb; i += 64) {
    const float* p = partials + ((size_t)row * nnb + i) * 2;
    float m2 = p[0], s2 = p[1];
    if (m2 > M) { float tt = M; M = m2; m2 = tt; tt = S; S = s2; s2 = tt; }
    if (s2 > 0.f) S += s2 * __expf(m2 - M);
  }
  for (int d = 1; d < 64; d <<= 1) {
    float m2 = __shfl_xor(M, d), s2 = __shfl_xor(S, d);
    if (m2 > M) { float tt = M; M = m2; m2 = tt; tt = S; S = s2; s2 = tt; }
    if (s2 > 0.f) S += s2 * __expf(m2 - M);
  }
  if (lane == 0) lse[row] = M + logf(S);
}

// ---------- logp = logits - lse[row] ----------
__global__ __launch_bounds__(256) void sub_lse_kernel(float* __restrict__ out,
                                                      const float* __restrict__ lse) {
  int i = blockIdx.x * 256 + threadIdx.x;  // < 8192000 float4s, 8000 per row
  int row = i / 8000;
  float l = lse[row];
  float4 v = reinterpret_cast<float4*>(out)[i];
  v.x -= l; v.y -= l; v.z -= l; v.w -= l;
  reinterpret_cast<float4*>(out)[i] = v;
}

extern "C" void kernel_launch(void* const* d_in, const int* in_sizes, int n_in,
                              void* d_out, int out_size, void* d_ws, size_t ws_size,
                              hipStream_t stream) {
  const int* tseq = (const int*)d_in[0];
  const float* thought = (const float*)d_in[1];
  const float* hidden = (const float*)d_in[2];
  const float* emb = (const float*)d_in[3];
  const float* W_ih = (const float*)d_in[4];
  const float* W_hh = (const float*)d_in[5];
  const float* b_ih = (const float*)d_in[6];
  const float* b_hh = (const float*)d_in[7];
  const float* W_out = (const float*)d_in[8];
  const float* b_out = (const float*)d_in[9];
  float* out = (float*)d_out;

  char* ws = (char*)d_ws;
  size_t off = 0;
  auto alloc = [&](size_t bytes) {
    void* p = ws + off;
    off = (off + bytes + 255) & ~(size_t)255;
    return p;
  };
  u16* wout_bf = (u16*)alloc((size_t)32000 * 512 * 2);
  u16* wih_bf  = (u16*)alloc((size_t)1536 * 1024 * 2);
  u16* x_bf    = (u16*)alloc((size_t)1024 * 1024 * 2);
  u16* ys_bf   = (u16*)alloc((size_t)1024 * 512 * 2);
  float* gi    = (float*)alloc((size_t)1024 * 1536 * 4);
  float* hbuf  = (float*)alloc((size_t)2 * 16 * 512 * 4);
  float* partials = (float*)alloc((size_t)1024 * 250 * 2 * 4);
  float* lse   = (float*)alloc((size_t)1024 * 4);
  int* flags   = (int*)alloc((size_t)16 * 32 * 4);
  (void)ws_size; (void)in_sizes; (void)n_in; (void)out_size;

  hipMemsetAsync(flags, 0, 16 * 32 * 4, stream);
  cvt_bf16_kernel<<<16000, 256, 0, stream>>>(W_out, wout_bf, 4096000);
  cvt_bf16_kernel<<<1536, 256, 0, stream>>>(W_ih, wih_bf, 393216);
  build_x_kernel<<<1024, 128, 0, stream>>>(tseq, emb, thought, x_bf);
  gemm_bt_kernel<false><<<dim3(12, 8), 256, 0, stream>>>(x_bf, wih_bf, b_ih, gi,
                                                         1024, 1536, 1024, nullptr, 0);
  gru_kernel<<<512, 128, 0, stream>>>(gi, W_hh, b_hh, hidden, hbuf, flags, ys_bf,
                                      out + 32768000);
  gemm_bt_kernel<true><<<dim3(250, 8), 256, 0, stream>>>(ys_bf, wout_bf, b_out, out,
                                                         1024, 32000, 512, partials, 250);
  lse_combine_kernel<<<1024, 64, 0, stream>>>(partials, lse, 250);
  sub_lse_kernel<<<32000, 256, 0, stream>>>(out, lse);
}

// Round 2
// 595.375 us; speedup vs baseline: 2.2797x; 2.2797x over previous
//
#include <hip/hip_runtime.h>

typedef unsigned int u32;
typedef unsigned short u16;
typedef short s16x8 __attribute__((ext_vector_type(8)));
typedef float f32x4 __attribute__((ext_vector_type(4)));

#define SENT 0xFFFFFFFFu

// ---------- helpers ----------
__device__ __forceinline__ u16 f2bf(float f) {
  u32 u = __float_as_uint(f);
  u32 r = (u + 0x7fffu + ((u >> 16) & 1u)) >> 16;  // RNE
  return (u16)r;
}

// ---------- fp32 -> bf16 convert (vectorized) ----------
__global__ __launch_bounds__(256) void cvt_bf16_kernel(const float* __restrict__ src,
                                                       u16* __restrict__ dst, int n4) {
  int i = blockIdx.x * 256 + threadIdx.x;
  if (i >= n4) return;
  float4 v = reinterpret_cast<const float4*>(src)[i];
  u32 lo = (u32)f2bf(v.x) | ((u32)f2bf(v.y) << 16);
  u32 hi = (u32)f2bf(v.z) | ((u32)f2bf(v.w) << 16);
  reinterpret_cast<uint2*>(dst)[i] = make_uint2(lo, hi);
}

// ---------- build x = [emb[tok] ; thought] as bf16, rows m = s*16+b, K=1024 ----------
__global__ __launch_bounds__(128) void build_x_kernel(const int* __restrict__ tseq,
                                                      const float* __restrict__ emb,
                                                      const float* __restrict__ thought,
                                                      u16* __restrict__ x) {
  int m = blockIdx.x;  // 0..1023, m = s*16 + b
  int s = m >> 4, b = m & 15;
  int tid = threadIdx.x;  // 128
  int k = tid * 8;
  const float* src;
  if (k < 512) src = emb + (size_t)tseq[b * 64 + s] * 512 + k;
  else         src = thought + b * 512 + (k - 512);
  float4 v0 = reinterpret_cast<const float4*>(src)[0];
  float4 v1 = reinterpret_cast<const float4*>(src)[1];
  uint4 o;
  o.x = (u32)f2bf(v0.x) | ((u32)f2bf(v0.y) << 16);
  o.y = (u32)f2bf(v0.z) | ((u32)f2bf(v0.w) << 16);
  o.z = (u32)f2bf(v1.x) | ((u32)f2bf(v1.y) << 16);
  o.w = (u32)f2bf(v1.z) | ((u32)f2bf(v1.w) << 16);
  *reinterpret_cast<uint4*>(x + (size_t)m * 1024 + k) = o;
}

// ---------- bf16 MFMA GEMM: C[M,N] = A[M,K] * B[N,K]^T + bias, optional LSE partials ----------
template <bool LSE>
__global__ __launch_bounds__(256) void gemm_bt_kernel(const u16* __restrict__ A,
                                                      const u16* __restrict__ Bm,
                                                      const float* __restrict__ bias,
                                                      float* __restrict__ C,
                                                      int M_, int N_, int K_,
                                                      float* __restrict__ partials, int nnb) {
  __shared__ u16 sA[128 * 40];
  __shared__ u16 sB[128 * 40];
  __shared__ float pm[2][128];
  __shared__ float ps[2][128];
  int nb = blockIdx.x, mb = blockIdx.y;
  int m0 = mb * 128, n0 = nb * 128;
  int tid = threadIdx.x;
  int wave = tid >> 6, lane = tid & 63;
  int wm = wave >> 1, wn = wave & 1;
  int l16 = lane & 15, quad = lane >> 4;
  int srow = tid >> 1, shalf = tid & 1;
  const u16* gA = A + (size_t)(m0 + srow) * K_ + shalf * 16;
  const u16* gB = Bm + (size_t)(n0 + srow) * K_ + shalf * 16;
  u16* lA = &sA[srow * 40 + shalf * 16];
  u16* lB = &sB[srow * 40 + shalf * 16];
  f32x4 acc[4][4];
  for (int i = 0; i < 4; ++i)
    for (int j = 0; j < 4; ++j) acc[i][j] = (f32x4){0.f, 0.f, 0.f, 0.f};

  for (int k0 = 0; k0 < K_; k0 += 32) {
    uint4 a0 = *reinterpret_cast<const uint4*>(gA + k0);
    uint4 a1 = *reinterpret_cast<const uint4*>(gA + k0 + 8);
    uint4 b0 = *reinterpret_cast<const uint4*>(gB + k0);
    uint4 b1 = *reinterpret_cast<const uint4*>(gB + k0 + 8);
    __syncthreads();
    *reinterpret_cast<uint4*>(lA) = a0;
    *reinterpret_cast<uint4*>(lA + 8) = a1;
    *reinterpret_cast<uint4*>(lB) = b0;
    *reinterpret_cast<uint4*>(lB + 8) = b1;
    __syncthreads();
    s16x8 af[4], bfr[4];
    for (int mt = 0; mt < 4; ++mt)
      af[mt] = *reinterpret_cast<const s16x8*>(&sA[(wm * 64 + mt * 16 + l16) * 40 + quad * 8]);
    for (int nt = 0; nt < 4; ++nt)
      bfr[nt] = *reinterpret_cast<const s16x8*>(&sB[(wn * 64 + nt * 16 + l16) * 40 + quad * 8]);
    for (int mt = 0; mt < 4; ++mt)
      for (int nt = 0; nt < 4; ++nt)
        acc[mt][nt] = __builtin_amdgcn_mfma_f32_16x16x32_bf16(af[mt], bfr[nt], acc[mt][nt], 0, 0, 0);
  }

  int rbase = wm * 64 + quad * 4;
  int cbase = n0 + wn * 64 + l16;
  for (int nt = 0; nt < 4; ++nt) {
    float bv = bias[cbase + nt * 16];
    for (int mt = 0; mt < 4; ++mt)
      for (int r = 0; r < 4; ++r) acc[mt][nt][r] += bv;
  }
  for (int mt = 0; mt < 4; ++mt)
    for (int r = 0; r < 4; ++r) {
      int row = m0 + rbase + mt * 16 + r;
      for (int nt = 0; nt < 4; ++nt)
        C[(size_t)row * N_ + cbase + nt * 16] = acc[mt][nt][r];
    }
  if (LSE) {
    for (int mt = 0; mt < 4; ++mt)
      for (int r = 0; r < 4; ++r) {
        float mx = acc[mt][0][r];
        for (int nt = 1; nt < 4; ++nt) mx = fmaxf(mx, acc[mt][nt][r]);
        for (int d = 1; d < 16; d <<= 1) mx = fmaxf(mx, __shfl_xor(mx, d));
        float sm = 0.f;
        for (int nt = 0; nt < 4; ++nt) sm += __expf(acc[mt][nt][r] - mx);
        for (int d = 1; d < 16; d <<= 1) sm += __shfl_xor(sm, d);
        if (l16 == 0) {
          int rr = wm * 64 + mt * 16 + quad * 4 + r;
          pm[wn][rr] = mx;
          ps[wn][rr] = sm;
        }
      }
    __syncthreads();
    if (tid < 128) {
      float m1 = pm[0][tid], m2 = pm[1][tid];
      float s1 = ps[0][tid], s2 = ps[1][tid];
      float Mx = fmaxf(m1, m2);
      float Sx = s1 * __expf(m1 - Mx) + s2 * __expf(m2 - Mx);
      float* p = partials + ((size_t)(m0 + tid) * nnb + nb) * 2;
      p[0] = Mx;
      p[1] = Sx;
    }
  }
}

// ---------- GRU recurrence, sentinel-sync version ----------
// 512 WGs = 16 batches x 32 row-slices; W slice (48x512 bf16) in LDS.
// hbase[t][b][j] is write-once: 0xFFFFFFFF sentinel until step-t writer stores it.
// Readers poll with RELAXED agent-scope loads (bypass L1/L2, no invalidate storms);
// writers use RELAXED agent-scope stores. No fences anywhere in the loop.
__global__ __launch_bounds__(128) void gru_kernel(const float* __restrict__ gi,
                                                  const float* __restrict__ W_hh,
                                                  const float* __restrict__ b_hh,
                                                  const float* __restrict__ hidden,
                                                  u32* __restrict__ hbase,  // [64][16][512]
                                                  u16* __restrict__ ys,     // [1024][512], m=b*64+t
                                                  float* __restrict__ hlast) {
  __shared__ u16 sW[48 * 520];   // padded stride 520
  __shared__ float h_s[576];     // padded: idx(j) = j + 4*(j>>5)
  __shared__ float gh_s[48];
  int wg = blockIdx.x;
  int b = wg >> 5, g = wg & 31;
  int tid = threadIdx.x;  // 128
  for (int lr = 0; lr < 48; ++lr) {
    int grow = (lr >> 4) * 512 + g * 16 + (lr & 15);
    const float* srcw = W_hh + (size_t)grow * 512;
    int k = tid * 4;
    float4 v = *reinterpret_cast<const float4*>(srcw + k);
    u16* dw = &sW[lr * 520 + k];
    dw[0] = f2bf(v.x); dw[1] = f2bf(v.y); dw[2] = f2bf(v.z); dw[3] = f2bf(v.w);
  }
  __syncthreads();
  int grp = tid >> 4, l16 = tid & 15;
  int j = g * 16 + (tid & 15);          // output index for tid<16
  float bhr = 0.f, bhz = 0.f, bhn = 0.f;
  if (tid < 16) { bhr = b_hh[j]; bhz = b_hh[512 + j]; bhn = b_hh[1024 + j]; }
  int j0 = tid, j1 = tid + 128, j2 = tid + 256, j3 = tid + 384;

  for (int t = 0; t < 64; ++t) {
    // issue this step's gi loads early (independent of h_{t-1})
    float gir = 0.f, giz = 0.f, gin = 0.f;
    if (tid < 16) {
      size_t gib = ((size_t)t * 16 + b) * 1536;
      gir = gi[gib + j]; giz = gi[gib + 512 + j]; gin = gi[gib + 1024 + j];
    }
    if (t > 0) {
      const u32* hp = hbase + (size_t)(t - 1) * 8192 + b * 512;
      u32 v0 = __hip_atomic_load(hp + j0, __ATOMIC_RELAXED, __HIP_MEMORY_SCOPE_AGENT);
      u32 v1 = __hip_atomic_load(hp + j1, __ATOMIC_RELAXED, __HIP_MEMORY_SCOPE_AGENT);
      u32 v2 = __hip_atomic_load(hp + j2, __ATOMIC_RELAXED, __HIP_MEMORY_SCOPE_AGENT);
      u32 v3 = __hip_atomic_load(hp + j3, __ATOMIC_RELAXED, __HIP_MEMORY_SCOPE_AGENT);
      while (v0 == SENT || v1 == SENT || v2 == SENT || v3 == SENT) {
        __builtin_amdgcn_s_sleep(1);
        if (v0 == SENT) v0 = __hip_atomic_load(hp + j0, __ATOMIC_RELAXED, __HIP_MEMORY_SCOPE_AGENT);
        if (v1 == SENT) v1 = __hip_atomic_load(hp + j1, __ATOMIC_RELAXED, __HIP_MEMORY_SCOPE_AGENT);
        if (v2 == SENT) v2 = __hip_atomic_load(hp + j2, __ATOMIC_RELAXED, __HIP_MEMORY_SCOPE_AGENT);
        if (v3 == SENT) v3 = __hip_atomic_load(hp + j3, __ATOMIC_RELAXED, __HIP_MEMORY_SCOPE_AGENT);
      }
      h_s[j0 + ((j0 >> 5) << 2)] = __uint_as_float(v0);
      h_s[j1 + ((j1 >> 5) << 2)] = __uint_as_float(v1);
      h_s[j2 + ((j2 >> 5) << 2)] = __uint_as_float(v2);
      h_s[j3 + ((j3 >> 5) << 2)] = __uint_as_float(v3);
    } else {
      const float* hp = hidden + b * 512;
      for (int jj = tid; jj < 512; jj += 128) h_s[jj + ((jj >> 5) << 2)] = hp[jj];
    }
    __syncthreads();
    // preload this lane's 32 h values (cols l16*32..+32)
    float hreg[32];
    int hb2 = l16 * 36;
    for (int c4 = 0; c4 < 4; ++c4) {
      float4 x0 = *reinterpret_cast<const float4*>(&h_s[hb2 + c4 * 8]);
      float4 x1 = *reinterpret_cast<const float4*>(&h_s[hb2 + c4 * 8 + 4]);
      hreg[c4 * 8 + 0] = x0.x; hreg[c4 * 8 + 1] = x0.y;
      hreg[c4 * 8 + 2] = x0.z; hreg[c4 * 8 + 3] = x0.w;
      hreg[c4 * 8 + 4] = x1.x; hreg[c4 * 8 + 5] = x1.y;
      hreg[c4 * 8 + 6] = x1.z; hreg[c4 * 8 + 7] = x1.w;
    }
    for (int p = 0; p < 6; ++p) {
      int lr = p * 8 + grp;
      const u16* wr = &sW[lr * 520 + l16 * 32];
      float acc = 0.f;
      for (int c4 = 0; c4 < 4; ++c4) {
        uint4 wv = *reinterpret_cast<const uint4*>(wr + c4 * 8);
        const float* hh = &hreg[c4 * 8];
        acc += __uint_as_float(wv.x << 16) * hh[0] + __uint_as_float(wv.x & 0xffff0000u) * hh[1];
        acc += __uint_as_float(wv.y << 16) * hh[2] + __uint_as_float(wv.y & 0xffff0000u) * hh[3];
        acc += __uint_as_float(wv.z << 16) * hh[4] + __uint_as_float(wv.z & 0xffff0000u) * hh[5];
        acc += __uint_as_float(wv.w << 16) * hh[6] + __uint_as_float(wv.w & 0xffff0000u) * hh[7];
      }
      acc += __shfl_xor(acc, 1);
      acc += __shfl_xor(acc, 2);
      acc += __shfl_xor(acc, 4);
      acc += __shfl_xor(acc, 8);
      if (l16 == 0) gh_s[lr] = acc;
    }
    __syncthreads();
    if (tid < 16) {
      float ghr = gh_s[tid] + bhr;
      float ghz = gh_s[16 + tid] + bhz;
      float ghn = gh_s[32 + tid] + bhn;
      float r = 1.f / (1.f + __expf(-(gir + ghr)));
      float z = 1.f / (1.f + __expf(-(giz + ghz)));
      float n = tanhf(gin + r * ghn);
      float hprev = h_s[j + ((j >> 5) << 2)];
      float hv = (1.f - z) * n + z * hprev;
      __hip_atomic_store(hbase + (size_t)t * 8192 + b * 512 + j, __float_as_uint(hv),
                         __ATOMIC_RELAXED, __HIP_MEMORY_SCOPE_AGENT);
      ys[((size_t)b * 64 + t) * 512 + j] = f2bf(hv);
      if (t == 63) hlast[b * 512 + j] = hv;
    }
    __syncthreads();
  }
}

// ---------- combine per-row LSE partials ----------
__global__ __launch_bounds__(64) void lse_combine_kernel(const float* __restrict__ partials,
                                                         float* __restrict__ lse, int nnb) {
  int row = blockIdx.x;
  int lane = threadIdx.x;
  float M = -INFINITY, S = 0.f;
  for (int i = lane; i < nnb; i += 64) {
    const float* p = partials + ((size_t)row * nnb + i) * 2;
    float m2 = p[0], s2 = p[1];
    if (m2 > M) { float tt = M; M = m2; m2 = tt; tt = S; S = s2; s2 = tt; }
    if (s2 > 0.f) S += s2 * __expf(m2 - M);
  }
  for (int d = 1; d < 64; d <<= 1) {
    float m2 = __shfl_xor(M, d), s2 = __shfl_xor(S, d);
    if (m2 > M) { float tt = M; M = m2; m2 = tt; tt = S; S = s2; s2 = tt; }
    if (s2 > 0.f) S += s2 * __expf(m2 - M);
  }
  if (lane == 0) lse[row] = M + logf(S);
}

// ---------- logp = logits - lse[row] ----------
__global__ __launch_bounds__(256) void sub_lse_kernel(float* __restrict__ out,
                                                      const float* __restrict__ lse) {
  int i = blockIdx.x * 256 + threadIdx.x;  // 8000 float4s per row
  int row = i / 8000;
  float l = lse[row];
  float4 v = reinterpret_cast<float4*>(out)[i];
  v.x -= l; v.y -= l; v.z -= l; v.w -= l;
  reinterpret_cast<float4*>(out)[i] = v;
}

extern "C" void kernel_launch(void* const* d_in, const int* in_sizes, int n_in,
                              void* d_out, int out_size, void* d_ws, size_t ws_size,
                              hipStream_t stream) {
  const int* tseq = (const int*)d_in[0];
  const float* thought = (const float*)d_in[1];
  const float* hidden = (const float*)d_in[2];
  const float* emb = (const float*)d_in[3];
  const float* W_ih = (const float*)d_in[4];
  const float* W_hh = (const float*)d_in[5];
  const float* b_ih = (const float*)d_in[6];
  const float* b_hh = (const float*)d_in[7];
  const float* W_out = (const float*)d_in[8];
  const float* b_out = (const float*)d_in[9];
  float* out = (float*)d_out;

  char* ws = (char*)d_ws;
  size_t off = 0;
  auto alloc = [&](size_t bytes) {
    void* p = ws + off;
    off = (off + bytes + 255) & ~(size_t)255;
    return p;
  };
  u16* wout_bf = (u16*)alloc((size_t)32000 * 512 * 2);
  u16* wih_bf  = (u16*)alloc((size_t)1536 * 1024 * 2);
  u16* x_bf    = (u16*)alloc((size_t)1024 * 1024 * 2);
  u16* ys_bf   = (u16*)alloc((size_t)1024 * 512 * 2);
  float* gi    = (float*)alloc((size_t)1024 * 1536 * 4);
  u32* hbase   = (u32*)alloc((size_t)64 * 16 * 512 * 4);
  float* partials = (float*)alloc((size_t)1024 * 250 * 2 * 4);
  float* lse   = (float*)alloc((size_t)1024 * 4);
  (void)ws_size; (void)in_sizes; (void)n_in; (void)out_size;

  hipMemsetAsync(hbase, 0xFF, (size_t)64 * 16 * 512 * 4, stream);  // NaN sentinel
  cvt_bf16_kernel<<<16000, 256, 0, stream>>>(W_out, wout_bf, 4096000);
  cvt_bf16_kernel<<<1536, 256, 0, stream>>>(W_ih, wih_bf, 393216);
  build_x_kernel<<<1024, 128, 0, stream>>>(tseq, emb, thought, x_bf);
  gemm_bt_kernel<false><<<dim3(12, 8), 256, 0, stream>>>(x_bf, wih_bf, b_ih, gi,
                                                         1024, 1536, 1024, nullptr, 0);
  gru_kernel<<<512, 128, 0, stream>>>(gi, W_hh, b_hh, hidden, hbase, ys_bf,
                                      out + 32768000);
  gemm_bt_kernel<true><<<dim3(250, 8), 256, 0, stream>>>(ys_bf, wout_bf, b_out, out,
                                                         1024, 32000, 512, partials, 250);
  lse_combine_kernel<<<1024, 64, 0, stream>>>(partials, lse, 250);
  sub_lse_kernel<<<32000, 256, 0, stream>>>(out, lse);
}

// Round 3
// 589.581 us; speedup vs baseline: 2.3021x; 1.0098x over previous
//
#include <hip/hip_runtime.h>

typedef unsigned int u32;
typedef unsigned short u16;
typedef short s16x8 __attribute__((ext_vector_type(8)));
typedef float f32x4 __attribute__((ext_vector_type(4)));

#define SENT 0xFFFFFFFFu

// ---------- helpers ----------
__device__ __forceinline__ u16 f2bf(float f) {
  u32 u = __float_as_uint(f);
  u32 r = (u + 0x7fffu + ((u >> 16) & 1u)) >> 16;  // RNE
  return (u16)r;
}

// L1/L2-bypassing 16B load (same cache path as agent-scope atomics)
__device__ __forceinline__ uint4 load_u4_bypass(const u32* p) {
  uint4 r;
  asm volatile("global_load_dwordx4 %0, %1, off sc0 sc1\n\ts_waitcnt vmcnt(0)"
               : "=v"(r) : "v"(p) : "memory");
  return r;
}

// ---------- fp32 -> bf16 convert (vectorized) ----------
__global__ __launch_bounds__(256) void cvt_bf16_kernel(const float* __restrict__ src,
                                                       u16* __restrict__ dst, int n4) {
  int i = blockIdx.x * 256 + threadIdx.x;
  if (i >= n4) return;
  float4 v = reinterpret_cast<const float4*>(src)[i];
  u32 lo = (u32)f2bf(v.x) | ((u32)f2bf(v.y) << 16);
  u32 hi = (u32)f2bf(v.z) | ((u32)f2bf(v.w) << 16);
  reinterpret_cast<uint2*>(dst)[i] = make_uint2(lo, hi);
}

// ---------- build x = [emb[tok] ; thought] as bf16, rows m = s*16+b, K=1024 ----------
__global__ __launch_bounds__(128) void build_x_kernel(const int* __restrict__ tseq,
                                                      const float* __restrict__ emb,
                                                      const float* __restrict__ thought,
                                                      u16* __restrict__ x) {
  int m = blockIdx.x;  // 0..1023, m = s*16 + b
  int s = m >> 4, b = m & 15;
  int tid = threadIdx.x;  // 128
  int k = tid * 8;
  const float* src;
  if (k < 512) src = emb + (size_t)tseq[b * 64 + s] * 512 + k;
  else         src = thought + b * 512 + (k - 512);
  float4 v0 = reinterpret_cast<const float4*>(src)[0];
  float4 v1 = reinterpret_cast<const float4*>(src)[1];
  uint4 o;
  o.x = (u32)f2bf(v0.x) | ((u32)f2bf(v0.y) << 16);
  o.y = (u32)f2bf(v0.z) | ((u32)f2bf(v0.w) << 16);
  o.z = (u32)f2bf(v1.x) | ((u32)f2bf(v1.y) << 16);
  o.w = (u32)f2bf(v1.z) | ((u32)f2bf(v1.w) << 16);
  *reinterpret_cast<uint4*>(x + (size_t)m * 1024 + k) = o;
}

// ---------- bf16 MFMA GEMM: C[M,N] = A[M,K] * B[N,K]^T + bias, optional LSE partials ----------
template <bool LSE>
__global__ __launch_bounds__(256) void gemm_bt_kernel(const u16* __restrict__ A,
                                                      const u16* __restrict__ Bm,
                                                      const float* __restrict__ bias,
                                                      float* __restrict__ C,
                                                      int M_, int N_, int K_,
                                                      float* __restrict__ partials, int nnb) {
  __shared__ u16 sA[128 * 40];
  __shared__ u16 sB[128 * 40];
  __shared__ float pm[2][128];
  __shared__ float ps[2][128];
  int nb = blockIdx.x, mb = blockIdx.y;
  int m0 = mb * 128, n0 = nb * 128;
  int tid = threadIdx.x;
  int wave = tid >> 6, lane = tid & 63;
  int wm = wave >> 1, wn = wave & 1;
  int l16 = lane & 15, quad = lane >> 4;
  int srow = tid >> 1, shalf = tid & 1;
  const u16* gA = A + (size_t)(m0 + srow) * K_ + shalf * 16;
  const u16* gB = Bm + (size_t)(n0 + srow) * K_ + shalf * 16;
  u16* lA = &sA[srow * 40 + shalf * 16];
  u16* lB = &sB[srow * 40 + shalf * 16];
  f32x4 acc[4][4];
  for (int i = 0; i < 4; ++i)
    for (int j = 0; j < 4; ++j) acc[i][j] = (f32x4){0.f, 0.f, 0.f, 0.f};

  for (int k0 = 0; k0 < K_; k0 += 32) {
    uint4 a0 = *reinterpret_cast<const uint4*>(gA + k0);
    uint4 a1 = *reinterpret_cast<const uint4*>(gA + k0 + 8);
    uint4 b0 = *reinterpret_cast<const uint4*>(gB + k0);
    uint4 b1 = *reinterpret_cast<const uint4*>(gB + k0 + 8);
    __syncthreads();
    *reinterpret_cast<uint4*>(lA) = a0;
    *reinterpret_cast<uint4*>(lA + 8) = a1;
    *reinterpret_cast<uint4*>(lB) = b0;
    *reinterpret_cast<uint4*>(lB + 8) = b1;
    __syncthreads();
    s16x8 af[4], bfr[4];
    for (int mt = 0; mt < 4; ++mt)
      af[mt] = *reinterpret_cast<const s16x8*>(&sA[(wm * 64 + mt * 16 + l16) * 40 + quad * 8]);
    for (int nt = 0; nt < 4; ++nt)
      bfr[nt] = *reinterpret_cast<const s16x8*>(&sB[(wn * 64 + nt * 16 + l16) * 40 + quad * 8]);
    for (int mt = 0; mt < 4; ++mt)
      for (int nt = 0; nt < 4; ++nt)
        acc[mt][nt] = __builtin_amdgcn_mfma_f32_16x16x32_bf16(af[mt], bfr[nt], acc[mt][nt], 0, 0, 0);
  }

  int rbase = wm * 64 + quad * 4;
  int cbase = n0 + wn * 64 + l16;
  for (int nt = 0; nt < 4; ++nt) {
    float bv = bias[cbase + nt * 16];
    for (int mt = 0; mt < 4; ++mt)
      for (int r = 0; r < 4; ++r) acc[mt][nt][r] += bv;
  }
  for (int mt = 0; mt < 4; ++mt)
    for (int r = 0; r < 4; ++r) {
      int row = m0 + rbase + mt * 16 + r;
      for (int nt = 0; nt < 4; ++nt)
        C[(size_t)row * N_ + cbase + nt * 16] = acc[mt][nt][r];
    }
  if (LSE) {
    for (int mt = 0; mt < 4; ++mt)
      for (int r = 0; r < 4; ++r) {
        float mx = acc[mt][0][r];
        for (int nt = 1; nt < 4; ++nt) mx = fmaxf(mx, acc[mt][nt][r]);
        for (int d = 1; d < 16; d <<= 1) mx = fmaxf(mx, __shfl_xor(mx, d));
        float sm = 0.f;
        for (int nt = 0; nt < 4; ++nt) sm += __expf(acc[mt][nt][r] - mx);
        for (int d = 1; d < 16; d <<= 1) sm += __shfl_xor(sm, d);
        if (l16 == 0) {
          int rr = wm * 64 + mt * 16 + quad * 4 + r;
          pm[wn][rr] = mx;
          ps[wn][rr] = sm;
        }
      }
    __syncthreads();
    if (tid < 128) {
      float m1 = pm[0][tid], m2 = pm[1][tid];
      float s1 = ps[0][tid], s2 = ps[1][tid];
      float Mx = fmaxf(m1, m2);
      float Sx = s1 * __expf(m1 - Mx) + s2 * __expf(m2 - Mx);
      float* p = partials + ((size_t)(m0 + tid) * nnb + nb) * 2;
      p[0] = Mx;
      p[1] = Sx;
    }
  }
}

// ---------- GRU recurrence, sentinel-sync, low-contention polling ----------
// 512 WGs = 16 batches x 32 row-slices; W slice (48x512 bf16) in LDS.
// hbase[t][b][j] write-once: SENT until step-t writer stores it (relaxed agent store).
// Readers: 32 lanes poll 1 flag word per writer group (its line's first element),
// then all 128 threads bulk-read 16B each via sc0|sc1 loads with sentinel
// re-validation (no reliance on line atomicity).
__global__ __launch_bounds__(128) void gru_kernel(const float* __restrict__ gi,
                                                  const float* __restrict__ W_hh,
                                                  const float* __restrict__ b_hh,
                                                  const float* __restrict__ hidden,
                                                  u32* __restrict__ hbase,  // [64][16][512]
                                                  u16* __restrict__ ys,     // [1024][512], m=b*64+t
                                                  float* __restrict__ hlast) {
  __shared__ u16 sW[48 * 520];   // padded stride 520
  __shared__ float h_s[576];     // padded: idx(j) = j + 4*(j>>5)
  __shared__ float gh_s[48];
  int wg = blockIdx.x;
  int b = wg >> 5, g = wg & 31;
  int tid = threadIdx.x;  // 128
  for (int lr = 0; lr < 48; ++lr) {
    int grow = (lr >> 4) * 512 + g * 16 + (lr & 15);
    const float* srcw = W_hh + (size_t)grow * 512;
    int k = tid * 4;
    float4 v = *reinterpret_cast<const float4*>(srcw + k);
    u16* dw = &sW[lr * 520 + k];
    dw[0] = f2bf(v.x); dw[1] = f2bf(v.y); dw[2] = f2bf(v.z); dw[3] = f2bf(v.w);
  }
  __syncthreads();
  int grp = tid >> 4, l16 = tid & 15;
  int j = g * 16 + (tid & 15);          // output index for tid<16
  float bhr = 0.f, bhz = 0.f, bhn = 0.f;
  if (tid < 16) { bhr = b_hh[j]; bhz = b_hh[512 + j]; bhn = b_hh[1024 + j]; }
  int j0 = tid * 4;                      // bulk-read base (16B per thread)

  for (int t = 0; t < 64; ++t) {
    // issue this step's gi loads early (independent of h_{t-1})
    float gir = 0.f, giz = 0.f, gin = 0.f;
    if (tid < 16) {
      size_t gib = ((size_t)t * 16 + b) * 1536;
      gir = gi[gib + j]; giz = gi[gib + 512 + j]; gin = gi[gib + 1024 + j];
    }
    if (t > 0) {
      const u32* hp = hbase + (size_t)(t - 1) * 8192 + b * 512;
      // phase 1: 32 lanes poll one flag word per writer group
      if (tid < 32) {
        const u32* fp = hp + tid * 16;
        u32 v = __hip_atomic_load(fp, __ATOMIC_RELAXED, __HIP_MEMORY_SCOPE_AGENT);
        while (v == SENT) {
          __builtin_amdgcn_s_sleep(2);
          v = __hip_atomic_load(fp, __ATOMIC_RELAXED, __HIP_MEMORY_SCOPE_AGENT);
        }
      }
      __syncthreads();
      // phase 2: bulk read 16B/thread, validate sentinels (normally 0 retries)
      uint4 v = load_u4_bypass(hp + j0);
      while (v.x == SENT || v.y == SENT || v.z == SENT || v.w == SENT) {
        __builtin_amdgcn_s_sleep(1);
        v = load_u4_bypass(hp + j0);
      }
      float4 f;
      f.x = __uint_as_float(v.x); f.y = __uint_as_float(v.y);
      f.z = __uint_as_float(v.z); f.w = __uint_as_float(v.w);
      *reinterpret_cast<float4*>(&h_s[j0 + ((j0 >> 5) << 2)]) = f;
    } else {
      const float* hp = hidden + b * 512;
      for (int jj = tid; jj < 512; jj += 128) h_s[jj + ((jj >> 5) << 2)] = hp[jj];
    }
    __syncthreads();
    // preload this lane's 32 h values (cols l16*32..+32)
    float hreg[32];
    int hb2 = l16 * 36;
    for (int c4 = 0; c4 < 4; ++c4) {
      float4 x0 = *reinterpret_cast<const float4*>(&h_s[hb2 + c4 * 8]);
      float4 x1 = *reinterpret_cast<const float4*>(&h_s[hb2 + c4 * 8 + 4]);
      hreg[c4 * 8 + 0] = x0.x; hreg[c4 * 8 + 1] = x0.y;
      hreg[c4 * 8 + 2] = x0.z; hreg[c4 * 8 + 3] = x0.w;
      hreg[c4 * 8 + 4] = x1.x; hreg[c4 * 8 + 5] = x1.y;
      hreg[c4 * 8 + 6] = x1.z; hreg[c4 * 8 + 7] = x1.w;
    }
    for (int p = 0; p < 6; ++p) {
      int lr = p * 8 + grp;
      const u16* wr = &sW[lr * 520 + l16 * 32];
      float acc = 0.f;
      for (int c4 = 0; c4 < 4; ++c4) {
        uint4 wv = *reinterpret_cast<const uint4*>(wr + c4 * 8);
        const float* hh = &hreg[c4 * 8];
        acc += __uint_as_float(wv.x << 16) * hh[0] + __uint_as_float(wv.x & 0xffff0000u) * hh[1];
        acc += __uint_as_float(wv.y << 16) * hh[2] + __uint_as_float(wv.y & 0xffff0000u) * hh[3];
        acc += __uint_as_float(wv.z << 16) * hh[4] + __uint_as_float(wv.z & 0xffff0000u) * hh[5];
        acc += __uint_as_float(wv.w << 16) * hh[6] + __uint_as_float(wv.w & 0xffff0000u) * hh[7];
      }
      acc += __shfl_xor(acc, 1);
      acc += __shfl_xor(acc, 2);
      acc += __shfl_xor(acc, 4);
      acc += __shfl_xor(acc, 8);
      if (l16 == 0) gh_s[lr] = acc;
    }
    __syncthreads();
    if (tid < 16) {
      float ghr = gh_s[tid] + bhr;
      float ghz = gh_s[16 + tid] + bhz;
      float ghn = gh_s[32 + tid] + bhn;
      float r = 1.f / (1.f + __expf(-(gir + ghr)));
      float z = 1.f / (1.f + __expf(-(giz + ghz)));
      float n = tanhf(gin + r * ghn);
      float hprev = h_s[j + ((j >> 5) << 2)];
      float hv = (1.f - z) * n + z * hprev;
      __hip_atomic_store(hbase + (size_t)t * 8192 + b * 512 + j, __float_as_uint(hv),
                         __ATOMIC_RELAXED, __HIP_MEMORY_SCOPE_AGENT);
      ys[((size_t)b * 64 + t) * 512 + j] = f2bf(hv);
      if (t == 63) hlast[b * 512 + j] = hv;
    }
    __syncthreads();
  }
}

// ---------- combine per-row LSE partials ----------
__global__ __launch_bounds__(64) void lse_combine_kernel(const float* __restrict__ partials,
                                                         float* __restrict__ lse, int nnb) {
  int row = blockIdx.x;
  int lane = threadIdx.x;
  float M = -INFINITY, S = 0.f;
  for (int i = lane; i < nnb; i += 64) {
    const float* p = partials + ((size_t)row * nnb + i) * 2;
    float m2 = p[0], s2 = p[1];
    if (m2 > M) { float tt = M; M = m2; m2 = tt; tt = S; S = s2; s2 = tt; }
    if (s2 > 0.f) S += s2 * __expf(m2 - M);
  }
  for (int d = 1; d < 64; d <<= 1) {
    float m2 = __shfl_xor(M, d), s2 = __shfl_xor(S, d);
    if (m2 > M) { float tt = M; M = m2; m2 = tt; tt = S; S = s2; s2 = tt; }
    if (s2 > 0.f) S += s2 * __expf(m2 - M);
  }
  if (lane == 0) lse[row] = M + logf(S);
}

// ---------- logp = logits - lse[row] ----------
__global__ __launch_bounds__(256) void sub_lse_kernel(float* __restrict__ out,
                                                      const float* __restrict__ lse) {
  int i = blockIdx.x * 256 + threadIdx.x;  // 8000 float4s per row
  int row = i / 8000;
  float l = lse[row];
  float4 v = reinterpret_cast<float4*>(out)[i];
  v.x -= l; v.y -= l; v.z -= l; v.w -= l;
  reinterpret_cast<float4*>(out)[i] = v;
}

extern "C" void kernel_launch(void* const* d_in, const int* in_sizes, int n_in,
                              void* d_out, int out_size, void* d_ws, size_t ws_size,
                              hipStream_t stream) {
  const int* tseq = (const int*)d_in[0];
  const float* thought = (const float*)d_in[1];
  const float* hidden = (const float*)d_in[2];
  const float* emb = (const float*)d_in[3];
  const float* W_ih = (const float*)d_in[4];
  const float* W_hh = (const float*)d_in[5];
  const float* b_ih = (const float*)d_in[6];
  const float* b_hh = (const float*)d_in[7];
  const float* W_out = (const float*)d_in[8];
  const float* b_out = (const float*)d_in[9];
  float* out = (float*)d_out;

  char* ws = (char*)d_ws;
  size_t off = 0;
  auto alloc = [&](size_t bytes) {
    void* p = ws + off;
    off = (off + bytes + 255) & ~(size_t)255;
    return p;
  };
  u16* wout_bf = (u16*)alloc((size_t)32000 * 512 * 2);
  u16* wih_bf  = (u16*)alloc((size_t)1536 * 1024 * 2);
  u16* x_bf    = (u16*)alloc((size_t)1024 * 1024 * 2);
  u16* ys_bf   = (u16*)alloc((size_t)1024 * 512 * 2);
  float* gi    = (float*)alloc((size_t)1024 * 1536 * 4);
  u32* hbase   = (u32*)alloc((size_t)64 * 16 * 512 * 4);
  float* partials = (float*)alloc((size_t)1024 * 250 * 2 * 4);
  float* lse   = (float*)alloc((size_t)1024 * 4);
  (void)ws_size; (void)in_sizes; (void)n_in; (void)out_size;

  hipMemsetAsync(hbase, 0xFF, (size_t)64 * 16 * 512 * 4, stream);  // NaN sentinel
  cvt_bf16_kernel<<<16000, 256, 0, stream>>>(W_out, wout_bf, 4096000);
  cvt_bf16_kernel<<<1536, 256, 0, stream>>>(W_ih, wih_bf, 393216);
  build_x_kernel<<<1024, 128, 0, stream>>>(tseq, emb, thought, x_bf);
  gemm_bt_kernel<false><<<dim3(12, 8), 256, 0, stream>>>(x_bf, wih_bf, b_ih, gi,
                                                         1024, 1536, 1024, nullptr, 0);
  gru_kernel<<<512, 128, 0, stream>>>(gi, W_hh, b_hh, hidden, hbase, ys_bf,
                                      out + 32768000);
  gemm_bt_kernel<true><<<dim3(250, 8), 256, 0, stream>>>(ys_bf, wout_bf, b_out, out,
                                                         1024, 32000, 512, partials, 250);
  lse_combine_kernel<<<1024, 64, 0, stream>>>(partials, lse, 250);
  sub_lse_kernel<<<32000, 256, 0, stream>>>(out, lse);
}